// Round 4
// baseline (28726.660 us; speedup 1.0000x reference)
//
#include <hip/hip_runtime.h>
#include <math.h>

#define NN 4096
#define MAX_SWEEPS 12

typedef float f2 __attribute__((ext_vector_type(2)));

// psi(k) = alpha*k in GF(2^6), primitive poly x^6 + x + 1. Orbit of 1 = all 63 masks.
constexpr int psi_step(int k) { return ((k << 1) & 63) ^ ((k & 32) ? 3 : 0); }
struct CycTab {
  int c[63];
  constexpr CycTab() : c{} {
    int x = 1;
    for (int j = 0; j < 63; ++j) { c[j] = x; x = psi_step(x); }
  }
};
static constexpr CycTab CYC{};

__device__ __forceinline__ float bperm(int addr, float x) {
  return __int_as_float(__builtin_amdgcn_ds_bpermute(addr, __float_as_int(x)));
}
// Within-wave LDS fence: waits all own LDS ops; "memory" clobber stops compiler
// from reordering LDS accesses across it. Replaces __syncthreads for the
// private-slice (per-wave) LDS usage -> waves never block on each other.
__device__ __forceinline__ void wave_lds_fence() {
  asm volatile("s_waitcnt lgkmcnt(0)" ::: "memory");
}

// cs={c,s}, xy={x,y} -> {c*x - s*y, s*x + c*y}   (2 packed-f32 ops)
__device__ __forceinline__ f2 colrot(f2 cs, f2 xy) {
  f2 t, d;
  asm("v_pk_mul_f32 %0, %1, %2 op_sel:[1,1] op_sel_hi:[0,1] neg_lo:[1,0]"
      : "=v"(t) : "v"(cs), "v"(xy));
  asm("v_pk_fma_f32 %0, %1, %2, %3 op_sel:[0,0,0] op_sel_hi:[1,0,1]"
      : "=v"(d) : "v"(cs), "v"(xy), "v"(t));
  return d;
}
// cs={c,st}, a, p -> {c*a.x - st*p.y, c*a.y - st*p.x}   (row update; p = shfl'd slot)
__device__ __forceinline__ f2 rowrot(f2 cs, f2 a, f2 p) {
  f2 t, d;
  asm("v_pk_mul_f32 %0, %1, %2 op_sel:[1,1] op_sel_hi:[1,0] neg_lo:[1,0] neg_hi:[1,0]"
      : "=v"(t) : "v"(cs), "v"(p));
  asm("v_pk_fma_f32 %0, %1, %2, %3 op_sel:[0,0,0] op_sel_hi:[0,1,1]"
      : "=v"(d) : "v"(cs), "v"(a), "v"(t));
  return d;
}

// 4 waves / 256-thread block, ONE MATRIX PER WAVE, no inter-wave coupling:
// each wave owns a private 4 KB staging slice + 64-entry angle table. Engine
// identical to the verified R3 kernel except the column-phase angle gather:
// (c,st) is written once per round to the angle table (ds_write_b64) and read
// per reg-pair as one ds_read_b64 (was 2 bpermutes) -> DS instrs/round 128->98.
__global__ __launch_bounds__(256, 4) void logeig_jacobi_pk4(
    const float* __restrict__ X, float* __restrict__ out) {
  __shared__ float SH[4][1024];  // per-wave 4 KB staging (prologue/epilogue)
  __shared__ f2 ANG[4][64];      // per-wave per-round angle table {c, st}
  const int tid = threadIdx.x;
  const int lane = tid & 63;
  const int wid = tid >> 6;
  const size_t base = ((size_t)blockIdx.x * 4 + wid) * NN;
  float* lds = SH[wid];
  f2* ang = ANG[wid];

  f2 a2[32], v2[32];

  // ---- prologue: stage 16 rows (4 KB) at a time; lane extracts its row in XOR layout ----
  {
    const float4* Xg = (const float4*)(X + base);
    float4* L4 = (float4*)lds;
    for (int ch = 0; ch < 4; ++ch) {
#pragma unroll
      for (int i = 0; i < 4; ++i) L4[lane + 64 * i] = Xg[ch * 256 + lane + 64 * i];
      wave_lds_fence();
      if ((lane >> 4) == ch) {  // my row lives in this chunk
        const int lr = (lane & 15) << 6;
#pragma unroll
        for (int r = 0; r < 64; ++r) {  // 16 lanes -> 16 distinct banks: conflict-free
          const float val = lds[lr + (lane ^ r)];
          if (r & 1) a2[r >> 1].y = val; else a2[r >> 1].x = val;
        }
      }
      wave_lds_fence();  // reads done before next chunk overwrites
    }
  }
#pragma unroll
  for (int t = 1; t < 32; ++t) { v2[t].x = 0.0f; v2[t].y = 0.0f; }
  v2[0].x = 1.0f; v2[0].y = 0.0f;

  // phi state (wave-uniform -> SGPRs): m = phi(1); Bj = phi(2^{j+1}).
  int m = 1, B0 = 2, B1 = 4, B2 = 8, B3 = 16, B4 = 32;

#pragma unroll 1
  for (int sw = 0; sw < MAX_SWEEPS; ++sw) {
#pragma unroll 1
    for (int rr = 0; rr < 63; ++rr) {
      const int maddr = (lane ^ m) << 2;  // shared bpermute address (angle+row phases)
      // ---- angles (apq symmetrized: both pair lanes get bit-identical c,s) ----
      const float mydg = a2[0].x;
      const float otdg = bperm(maddr, mydg);
      const float apq = 0.5f * (a2[0].y + bperm(maddr, a2[0].y));
      const bool isq = (lane ^ m) < lane;
      const float app = isq ? otdg : mydg;
      const float aqq = isq ? mydg : otdg;
      float c = 1.0f, s = 0.0f;
      if (fabsf(apq) > 1e-37f) {
        const float tau = (aqq - app) / (2.0f * apq);
        float tt = 1.0f / (fabsf(tau) + sqrtf(1.0f + tau * tau));
        tt = (tau >= 0.0f) ? tt : -tt;
        c = rsqrtf(1.0f + tt * tt);  // deterministic + identical in both pair lanes
        s = tt * c;
      }
      const float st = isq ? -s : s;  // sign-folded s
      const f2 cst0 = {c, st};
      ang[lane] = cst0;  // publish angle for column-phase gathers
      wave_lds_fence();

      // ---- column rotations (A and V), Gray-ordered slots ----
      // Reg pair slot holds columns {lane^u, lane^u^m}; angle read from table
      // entry lane^u (one ds_read_b64), u Gray-walked via basis images Bj.
      {
        const int Bv[5] = {B0, B1, B2, B3, B4};
        int ui = lane;  // lane ^ u
#pragma unroll
        for (int t = 0; t < 32; ++t) {
          const int slot = t ^ (t >> 1);
          const f2 csg = (t == 0) ? cst0 : ang[ui];
          a2[slot] = colrot(csg, a2[slot]);
          v2[slot] = colrot(csg, v2[slot]);
          if (t < 31) ui ^= Bv[__builtin_ctz(t + 1)];
        }
      }

      // ---- row rotations: partner slot value via 2 bpermutes sharing maddr ----
#pragma unroll
      for (int t = 0; t < 32; ++t) {
        f2 p;
        p.x = bperm(maddr, a2[t].x);
        p.y = bperm(maddr, a2[t].y);
        a2[t] = rowrot(cst0, a2[t], p);
      }

      // ---- relabel a[k] <- a[psi(k)] (fixed 63-cycle, component-static after unroll) ----
      {
        const int h = CYC.c[0];
        const float ta = (h & 1) ? a2[h >> 1].y : a2[h >> 1].x;
        const float tv = (h & 1) ? v2[h >> 1].y : v2[h >> 1].x;
#pragma unroll
        for (int j = 0; j < 62; ++j) {
          const int dd = CYC.c[j], ss2 = CYC.c[j + 1];
          const float sa = (ss2 & 1) ? a2[ss2 >> 1].y : a2[ss2 >> 1].x;
          const float sv = (ss2 & 1) ? v2[ss2 >> 1].y : v2[ss2 >> 1].x;
          if (dd & 1) { a2[dd >> 1].y = sa; v2[dd >> 1].y = sv; }
          else        { a2[dd >> 1].x = sa; v2[dd >> 1].x = sv; }
        }
        const int l_ = CYC.c[62];
        if (l_ & 1) { a2[l_ >> 1].y = ta; v2[l_ >> 1].y = tv; }
        else        { a2[l_ >> 1].x = ta; v2[l_ >> 1].x = tv; }
      }

      // ---- advance phi ----
      const int nB4 = m ^ B0;
      m = B0; B0 = B1; B1 = B2; B2 = B3; B3 = B4; B4 = nB4;
    }

    // ---- convergence check (phi = identity here) ----
    float offs = a2[0].y * a2[0].y, dias = a2[0].x * a2[0].x;
#pragma unroll
    for (int t = 1; t < 32; ++t) {
      offs = fmaf(a2[t].x, a2[t].x, offs);
      offs = fmaf(a2[t].y, a2[t].y, offs);
    }
#pragma unroll
    for (int o = 1; o < 64; o <<= 1) {  // butterfly: all lanes identical -> uniform branch
      offs += __shfl_xor(offs, o);
      dias += __shfl_xor(dias, o);
    }
    if (offs <= 1e-13f * dias) break;
  }

  // ---- epilogue: Y = V diag(log lam) V^T, tiled 16 rows / 4 KB, per-wave private ----
  const float ll = logf(fmaxf(a2[0].x, 1e-30f));  // clamp: never NaN/inf
  // a2 is dead: reuse as la[r] = log lam of column lane^r
#pragma unroll
  for (int r = 0; r < 64; ++r) {
    const float lr_ = __shfl_xor(ll, r);
    if (r & 1) a2[r >> 1].y = lr_; else a2[r >> 1].x = lr_;
  }
  float* Og = out + base;
  for (int tt = 0; tt < 4; ++tt) {
    if ((lane >> 4) == tt) {  // write W rows of this tile (16 lanes, distinct banks)
      const int lr = (lane & 15) << 6;
#pragma unroll
      for (int t = 0; t < 32; ++t) {
        const f2 w = v2[t] * a2[t];
        lds[lr + ((2 * t) ^ lane)] = w.x;
        lds[lr + ((2 * t + 1) ^ lane)] = w.y;
      }
    }
    wave_lds_fence();
#pragma unroll 1
    for (int ii = 0; ii < 16; ++ii) {  // all lanes: Y[row][lane]; 2 lanes/bank = free
      const float* Wrow = lds + (ii << 6);
      float acc0 = 0.0f, acc1 = 0.0f;
#pragma unroll
      for (int t = 0; t < 32; ++t) {
        acc0 = fmaf(Wrow[lane ^ (2 * t)], v2[t].x, acc0);
        acc1 = fmaf(Wrow[lane ^ (2 * t + 1)], v2[t].y, acc1);
      }
      Og[((tt << 4) + ii) * 64 + lane] = acc0 + acc1;
    }
    wave_lds_fence();  // reads done before next tile overwrites
  }
}

extern "C" void kernel_launch(void* const* d_in, const int* in_sizes, int n_in,
                              void* d_out, int out_size, void* d_ws, size_t ws_size,
                              hipStream_t stream) {
  const float* X = (const float*)d_in[0];
  float* out = (float*)d_out;
  const int nmat = in_sizes[0] / NN;  // 8192
  logeig_jacobi_pk4<<<nmat / 4, 256, 0, stream>>>(X, out);
}

// Round 5
// 6507.796 us; speedup vs baseline: 4.4142x; 4.4142x over previous
//
#include <hip/hip_runtime.h>
#include <math.h>

#define NN 4096
#define MAX_SWEEPS 12

typedef float f2 __attribute__((ext_vector_type(2)));

// psi(k) = alpha*k in GF(2^6), primitive poly x^6 + x + 1. Orbit of 1 = all 63 masks.
constexpr int psi_step(int k) { return ((k << 1) & 63) ^ ((k & 32) ? 3 : 0); }
struct CycTab {
  int c[63];
  constexpr CycTab() : c{} {
    int x = 1;
    for (int j = 0; j < 63; ++j) { c[j] = x; x = psi_step(x); }
  }
};
static constexpr CycTab CYC{};

__device__ __forceinline__ float bperm(int addr, float x) {
  return __int_as_float(__builtin_amdgcn_ds_bpermute(addr, __float_as_int(x)));
}
// Within-wave LDS fence: waits all own LDS ops; "memory" clobber stops compiler
// from reordering LDS accesses across it. Replaces __syncthreads for the
// private-slice (per-wave) LDS usage -> waves never block on each other.
__device__ __forceinline__ void wave_lds_fence() {
  asm volatile("s_waitcnt lgkmcnt(0)" ::: "memory");
}

// cs={c,s}, xy={x,y} -> {c*x - s*y, s*x + c*y}   (2 packed-f32 ops)
__device__ __forceinline__ f2 colrot(f2 cs, f2 xy) {
  f2 t, d;
  asm("v_pk_mul_f32 %0, %1, %2 op_sel:[1,1] op_sel_hi:[0,1] neg_lo:[1,0]"
      : "=v"(t) : "v"(cs), "v"(xy));
  asm("v_pk_fma_f32 %0, %1, %2, %3 op_sel:[0,0,0] op_sel_hi:[1,0,1]"
      : "=v"(d) : "v"(cs), "v"(xy), "v"(t));
  return d;
}
// cs={c,st}, a, p -> {c*a.x - st*p.y, c*a.y - st*p.x}   (row update; p = shfl'd slot)
__device__ __forceinline__ f2 rowrot(f2 cs, f2 a, f2 p) {
  f2 t, d;
  asm("v_pk_mul_f32 %0, %1, %2 op_sel:[1,1] op_sel_hi:[1,0] neg_lo:[1,0] neg_hi:[1,0]"
      : "=v"(t) : "v"(cs), "v"(p));
  asm("v_pk_fma_f32 %0, %1, %2, %3 op_sel:[0,0,0] op_sel_hi:[0,1,1]"
      : "=v"(d) : "v"(cs), "v"(a), "v"(t));
  return d;
}

// 4 waves / 256-thread block, ONE MATRIX PER WAVE, no inter-wave coupling:
// each wave owns a private 4 KB staging slice + 64-entry angle table.
// launch_bounds(256,3): VGPR ceiling 170 -- R4's (256,4) hard 128-cap made the
// allocator spill the whole a2/v2 state to scratch (47+92 GB HBM traffic).
// The engine wants ~128-140 regs; give it headroom, no cliff.
__global__ __launch_bounds__(256, 3) void logeig_jacobi_pk4(
    const float* __restrict__ X, float* __restrict__ out) {
  __shared__ float SH[4][1024];  // per-wave 4 KB staging (prologue/epilogue)
  __shared__ f2 ANG[4][64];      // per-wave per-round angle table {c, st}
  const int tid = threadIdx.x;
  const int lane = tid & 63;
  const int wid = tid >> 6;
  const size_t base = ((size_t)blockIdx.x * 4 + wid) * NN;
  float* lds = SH[wid];
  f2* ang = ANG[wid];

  f2 a2[32], v2[32];

  // ---- prologue: stage 16 rows (4 KB) at a time; lane extracts its row in XOR layout ----
  {
    const float4* Xg = (const float4*)(X + base);
    float4* L4 = (float4*)lds;
    for (int ch = 0; ch < 4; ++ch) {
#pragma unroll
      for (int i = 0; i < 4; ++i) L4[lane + 64 * i] = Xg[ch * 256 + lane + 64 * i];
      wave_lds_fence();
      if ((lane >> 4) == ch) {  // my row lives in this chunk
        const int lr = (lane & 15) << 6;
#pragma unroll
        for (int r = 0; r < 64; ++r) {  // 16 lanes -> 16 distinct banks: conflict-free
          const float val = lds[lr + (lane ^ r)];
          if (r & 1) a2[r >> 1].y = val; else a2[r >> 1].x = val;
        }
      }
      wave_lds_fence();  // reads done before next chunk overwrites
    }
  }
#pragma unroll
  for (int t = 1; t < 32; ++t) { v2[t].x = 0.0f; v2[t].y = 0.0f; }
  v2[0].x = 1.0f; v2[0].y = 0.0f;

  // phi state (wave-uniform -> SGPRs): m = phi(1); Bj = phi(2^{j+1}).
  int m = 1, B0 = 2, B1 = 4, B2 = 8, B3 = 16, B4 = 32;

#pragma unroll 1
  for (int sw = 0; sw < MAX_SWEEPS; ++sw) {
#pragma unroll 1
    for (int rr = 0; rr < 63; ++rr) {
      const int maddr = (lane ^ m) << 2;  // shared bpermute address (angle+row phases)
      // ---- angles (apq symmetrized: both pair lanes get bit-identical c,s) ----
      const float mydg = a2[0].x;
      const float otdg = bperm(maddr, mydg);
      const float apq = 0.5f * (a2[0].y + bperm(maddr, a2[0].y));
      const bool isq = (lane ^ m) < lane;
      const float app = isq ? otdg : mydg;
      const float aqq = isq ? mydg : otdg;
      float c = 1.0f, s = 0.0f;
      if (fabsf(apq) > 1e-37f) {
        const float tau = (aqq - app) / (2.0f * apq);
        float tt = 1.0f / (fabsf(tau) + sqrtf(1.0f + tau * tau));
        tt = (tau >= 0.0f) ? tt : -tt;
        c = rsqrtf(1.0f + tt * tt);  // deterministic + identical in both pair lanes
        s = tt * c;
      }
      const float st = isq ? -s : s;  // sign-folded s
      const f2 cst0 = {c, st};
      ang[lane] = cst0;  // publish angle for column-phase gathers
      wave_lds_fence();

      // ---- column rotations (A and V), Gray-ordered slots ----
      // Reg pair slot holds columns {lane^u, lane^u^m}; angle read from table
      // entry lane^u (one ds_read_b64), u Gray-walked via basis images Bj.
      {
        const int Bv[5] = {B0, B1, B2, B3, B4};
        int ui = lane;  // lane ^ u
#pragma unroll
        for (int t = 0; t < 32; ++t) {
          const int slot = t ^ (t >> 1);
          const f2 csg = (t == 0) ? cst0 : ang[ui];
          a2[slot] = colrot(csg, a2[slot]);
          v2[slot] = colrot(csg, v2[slot]);
          if (t < 31) ui ^= Bv[__builtin_ctz(t + 1)];
        }
      }

      // ---- row rotations: partner slot value via 2 bpermutes sharing maddr ----
#pragma unroll
      for (int t = 0; t < 32; ++t) {
        f2 p;
        p.x = bperm(maddr, a2[t].x);
        p.y = bperm(maddr, a2[t].y);
        a2[t] = rowrot(cst0, a2[t], p);
      }

      // ---- relabel a[k] <- a[psi(k)] (fixed 63-cycle, component-static after unroll) ----
      {
        const int h = CYC.c[0];
        const float ta = (h & 1) ? a2[h >> 1].y : a2[h >> 1].x;
        const float tv = (h & 1) ? v2[h >> 1].y : v2[h >> 1].x;
#pragma unroll
        for (int j = 0; j < 62; ++j) {
          const int dd = CYC.c[j], ss2 = CYC.c[j + 1];
          const float sa = (ss2 & 1) ? a2[ss2 >> 1].y : a2[ss2 >> 1].x;
          const float sv = (ss2 & 1) ? v2[ss2 >> 1].y : v2[ss2 >> 1].x;
          if (dd & 1) { a2[dd >> 1].y = sa; v2[dd >> 1].y = sv; }
          else        { a2[dd >> 1].x = sa; v2[dd >> 1].x = sv; }
        }
        const int l_ = CYC.c[62];
        if (l_ & 1) { a2[l_ >> 1].y = ta; v2[l_ >> 1].y = tv; }
        else        { a2[l_ >> 1].x = ta; v2[l_ >> 1].x = tv; }
      }

      // ---- advance phi ----
      const int nB4 = m ^ B0;
      m = B0; B0 = B1; B1 = B2; B2 = B3; B3 = B4; B4 = nB4;
    }

    // ---- convergence check (phi = identity here) ----
    float offs = a2[0].y * a2[0].y, dias = a2[0].x * a2[0].x;
#pragma unroll
    for (int t = 1; t < 32; ++t) {
      offs = fmaf(a2[t].x, a2[t].x, offs);
      offs = fmaf(a2[t].y, a2[t].y, offs);
    }
#pragma unroll
    for (int o = 1; o < 64; o <<= 1) {  // butterfly: all lanes identical -> uniform branch
      offs += __shfl_xor(offs, o);
      dias += __shfl_xor(dias, o);
    }
    if (offs <= 1e-13f * dias) break;
  }

  // ---- epilogue: Y = V diag(log lam) V^T, tiled 16 rows / 4 KB, per-wave private ----
  const float ll = logf(fmaxf(a2[0].x, 1e-30f));  // clamp: never NaN/inf
  // a2 is dead: reuse as la[r] = log lam of column lane^r
#pragma unroll
  for (int r = 0; r < 64; ++r) {
    const float lr_ = __shfl_xor(ll, r);
    if (r & 1) a2[r >> 1].y = lr_; else a2[r >> 1].x = lr_;
  }
  float* Og = out + base;
  for (int tt = 0; tt < 4; ++tt) {
    if ((lane >> 4) == tt) {  // write W rows of this tile (16 lanes, distinct banks)
      const int lr = (lane & 15) << 6;
#pragma unroll
      for (int t = 0; t < 32; ++t) {
        const f2 w = v2[t] * a2[t];
        lds[lr + ((2 * t) ^ lane)] = w.x;
        lds[lr + ((2 * t + 1) ^ lane)] = w.y;
      }
    }
    wave_lds_fence();
#pragma unroll 1
    for (int ii = 0; ii < 16; ++ii) {  // all lanes: Y[row][lane]; 2 lanes/bank = free
      const float* Wrow = lds + (ii << 6);
      float acc0 = 0.0f, acc1 = 0.0f;
#pragma unroll
      for (int t = 0; t < 32; ++t) {
        acc0 = fmaf(Wrow[lane ^ (2 * t)], v2[t].x, acc0);
        acc1 = fmaf(Wrow[lane ^ (2 * t + 1)], v2[t].y, acc1);
      }
      Og[((tt << 4) + ii) * 64 + lane] = acc0 + acc1;
    }
    wave_lds_fence();  // reads done before next tile overwrites
  }
}

extern "C" void kernel_launch(void* const* d_in, const int* in_sizes, int n_in,
                              void* d_out, int out_size, void* d_ws, size_t ws_size,
                              hipStream_t stream) {
  const float* X = (const float*)d_in[0];
  float* out = (float*)d_out;
  const int nmat = in_sizes[0] / NN;  // 8192
  logeig_jacobi_pk4<<<nmat / 4, 256, 0, stream>>>(X, out);
}

// Round 6
// 5862.143 us; speedup vs baseline: 4.9004x; 1.1101x over previous
//
#include <hip/hip_runtime.h>
#include <math.h>

#define NN 4096
#define MAX_SWEEPS 12

typedef float f2 __attribute__((ext_vector_type(2)));

// psi(k) = alpha*k in GF(2^6), primitive poly x^6 + x + 1. Orbit of 1 = all 63 masks.
constexpr int psi_step(int k) { return ((k << 1) & 63) ^ ((k & 32) ? 3 : 0); }
struct CycTab {
  int c[63];
  constexpr CycTab() : c{} {
    int x = 1;
    for (int j = 0; j < 63; ++j) { c[j] = x; x = psi_step(x); }
  }
};
static constexpr CycTab CYC{};

__device__ __forceinline__ float bperm(int addr, float x) {
  return __int_as_float(__builtin_amdgcn_ds_bpermute(addr, __float_as_int(x)));
}
// Within-wave LDS fence: waits all own LDS ops; "memory" clobber stops compiler
// from reordering LDS accesses across it. Replaces __syncthreads for the
// private-slice (per-wave) LDS usage -> waves never block on each other.
__device__ __forceinline__ void wave_lds_fence() {
  asm volatile("s_waitcnt lgkmcnt(0)" ::: "memory");
}

// cs={c,s}, xy={x,y} -> {c*x - s*y, s*x + c*y}   (2 packed-f32 ops)
__device__ __forceinline__ f2 colrot(f2 cs, f2 xy) {
  f2 t, d;
  asm("v_pk_mul_f32 %0, %1, %2 op_sel:[1,1] op_sel_hi:[0,1] neg_lo:[1,0]"
      : "=v"(t) : "v"(cs), "v"(xy));
  asm("v_pk_fma_f32 %0, %1, %2, %3 op_sel:[0,0,0] op_sel_hi:[1,0,1]"
      : "=v"(d) : "v"(cs), "v"(xy), "v"(t));
  return d;
}
// cs={c,st}, a, p -> {c*a.x - st*p.y, c*a.y - st*p.x}   (row update; p = shfl'd slot)
__device__ __forceinline__ f2 rowrot(f2 cs, f2 a, f2 p) {
  f2 t, d;
  asm("v_pk_mul_f32 %0, %1, %2 op_sel:[1,1] op_sel_hi:[1,0] neg_lo:[1,0] neg_hi:[1,0]"
      : "=v"(t) : "v"(cs), "v"(p));
  asm("v_pk_fma_f32 %0, %1, %2, %3 op_sel:[0,0,0] op_sel_hi:[0,1,1]"
      : "=v"(d) : "v"(cs), "v"(a), "v"(t));
  return d;
}

// 4 waves / 256-thread block, ONE MATRIX PER WAVE, no inter-wave coupling.
// Register budget history: (256,4) -> hard 128-cap, full state spill, 29 ms.
// (256,3) -> combined-file budget ~170 split ~84 arch + AGPR, residual scratch
// spill (1.9 GB/dispatch HBM), 6.5 ms. (256,2) -> budget 256: engine fits in
// ~128 arch VGPRs (proven by the 64-thread build), zero scratch. Runtime
// occupancy follows ACTUAL VGPR count (<=128 -> 4 waves/SIMD), not the
// promised minimum.
__global__ __launch_bounds__(256, 2) void logeig_jacobi_pk4(
    const float* __restrict__ X, float* __restrict__ out) {
  __shared__ float SH[4][1024];  // per-wave 4 KB staging (prologue/epilogue)
  __shared__ f2 ANG[4][64];      // per-wave per-round angle table {c, st}
  const int tid = threadIdx.x;
  const int lane = tid & 63;
  const int wid = tid >> 6;
  const size_t base = ((size_t)blockIdx.x * 4 + wid) * NN;
  float* lds = SH[wid];
  f2* ang = ANG[wid];

  f2 a2[32], v2[32];

  // ---- prologue: stage 16 rows (4 KB) at a time; lane extracts its row in XOR layout ----
  {
    const float4* Xg = (const float4*)(X + base);
    float4* L4 = (float4*)lds;
    for (int ch = 0; ch < 4; ++ch) {
#pragma unroll
      for (int i = 0; i < 4; ++i) L4[lane + 64 * i] = Xg[ch * 256 + lane + 64 * i];
      wave_lds_fence();
      if ((lane >> 4) == ch) {  // my row lives in this chunk
        const int lr = (lane & 15) << 6;
#pragma unroll
        for (int r = 0; r < 64; ++r) {  // 16 lanes -> 16 distinct banks: conflict-free
          const float val = lds[lr + (lane ^ r)];
          if (r & 1) a2[r >> 1].y = val; else a2[r >> 1].x = val;
        }
      }
      wave_lds_fence();  // reads done before next chunk overwrites
    }
  }
#pragma unroll
  for (int t = 1; t < 32; ++t) { v2[t].x = 0.0f; v2[t].y = 0.0f; }
  v2[0].x = 1.0f; v2[0].y = 0.0f;

  // phi state (wave-uniform -> SGPRs): m = phi(1); Bj = phi(2^{j+1}).
  int m = 1, B0 = 2, B1 = 4, B2 = 8, B3 = 16, B4 = 32;

#pragma unroll 1
  for (int sw = 0; sw < MAX_SWEEPS; ++sw) {
#pragma unroll 1
    for (int rr = 0; rr < 63; ++rr) {
      const int maddr = (lane ^ m) << 2;  // shared bpermute address (angle+row phases)
      // ---- angles (apq symmetrized: both pair lanes get bit-identical c,s) ----
      const float mydg = a2[0].x;
      const float otdg = bperm(maddr, mydg);
      const float apq = 0.5f * (a2[0].y + bperm(maddr, a2[0].y));
      const bool isq = (lane ^ m) < lane;
      const float app = isq ? otdg : mydg;
      const float aqq = isq ? mydg : otdg;
      float c = 1.0f, s = 0.0f;
      if (fabsf(apq) > 1e-37f) {
        const float tau = (aqq - app) / (2.0f * apq);
        float tt = 1.0f / (fabsf(tau) + sqrtf(1.0f + tau * tau));
        tt = (tau >= 0.0f) ? tt : -tt;
        c = rsqrtf(1.0f + tt * tt);  // deterministic + identical in both pair lanes
        s = tt * c;
      }
      const float st = isq ? -s : s;  // sign-folded s
      const f2 cst0 = {c, st};
      ang[lane] = cst0;  // publish angle for column-phase gathers
      wave_lds_fence();

      // ---- column rotations (A and V), Gray-ordered slots ----
      // Reg pair slot holds columns {lane^u, lane^u^m}; angle read from table
      // entry lane^u (one ds_read_b64), u Gray-walked via basis images Bj.
      {
        const int Bv[5] = {B0, B1, B2, B3, B4};
        int ui = lane;  // lane ^ u
#pragma unroll
        for (int t = 0; t < 32; ++t) {
          const int slot = t ^ (t >> 1);
          const f2 csg = (t == 0) ? cst0 : ang[ui];
          a2[slot] = colrot(csg, a2[slot]);
          v2[slot] = colrot(csg, v2[slot]);
          if (t < 31) ui ^= Bv[__builtin_ctz(t + 1)];
        }
      }

      // ---- row rotations: partner slot value via 2 bpermutes sharing maddr ----
#pragma unroll
      for (int t = 0; t < 32; ++t) {
        f2 p;
        p.x = bperm(maddr, a2[t].x);
        p.y = bperm(maddr, a2[t].y);
        a2[t] = rowrot(cst0, a2[t], p);
      }

      // ---- relabel a[k] <- a[psi(k)] (fixed 63-cycle, component-static after unroll) ----
      {
        const int h = CYC.c[0];
        const float ta = (h & 1) ? a2[h >> 1].y : a2[h >> 1].x;
        const float tv = (h & 1) ? v2[h >> 1].y : v2[h >> 1].x;
#pragma unroll
        for (int j = 0; j < 62; ++j) {
          const int dd = CYC.c[j], ss2 = CYC.c[j + 1];
          const float sa = (ss2 & 1) ? a2[ss2 >> 1].y : a2[ss2 >> 1].x;
          const float sv = (ss2 & 1) ? v2[ss2 >> 1].y : v2[ss2 >> 1].x;
          if (dd & 1) { a2[dd >> 1].y = sa; v2[dd >> 1].y = sv; }
          else        { a2[dd >> 1].x = sa; v2[dd >> 1].x = sv; }
        }
        const int l_ = CYC.c[62];
        if (l_ & 1) { a2[l_ >> 1].y = ta; v2[l_ >> 1].y = tv; }
        else        { a2[l_ >> 1].x = ta; v2[l_ >> 1].x = tv; }
      }

      // ---- advance phi ----
      const int nB4 = m ^ B0;
      m = B0; B0 = B1; B1 = B2; B2 = B3; B3 = B4; B4 = nB4;
    }

    // ---- convergence check (phi = identity here) ----
    float offs = a2[0].y * a2[0].y, dias = a2[0].x * a2[0].x;
#pragma unroll
    for (int t = 1; t < 32; ++t) {
      offs = fmaf(a2[t].x, a2[t].x, offs);
      offs = fmaf(a2[t].y, a2[t].y, offs);
    }
#pragma unroll
    for (int o = 1; o < 64; o <<= 1) {  // butterfly: all lanes identical -> uniform branch
      offs += __shfl_xor(offs, o);
      dias += __shfl_xor(dias, o);
    }
    if (offs <= 1e-13f * dias) break;
  }

  // ---- epilogue: Y = V diag(log lam) V^T, tiled 16 rows / 4 KB, per-wave private ----
  const float ll = logf(fmaxf(a2[0].x, 1e-30f));  // clamp: never NaN/inf
  // a2 is dead: reuse as la[r] = log lam of column lane^r
#pragma unroll
  for (int r = 0; r < 64; ++r) {
    const float lr_ = __shfl_xor(ll, r);
    if (r & 1) a2[r >> 1].y = lr_; else a2[r >> 1].x = lr_;
  }
  float* Og = out + base;
  for (int tt = 0; tt < 4; ++tt) {
    if ((lane >> 4) == tt) {  // write W rows of this tile (16 lanes, distinct banks)
      const int lr = (lane & 15) << 6;
#pragma unroll
      for (int t = 0; t < 32; ++t) {
        const f2 w = v2[t] * a2[t];
        lds[lr + ((2 * t) ^ lane)] = w.x;
        lds[lr + ((2 * t + 1) ^ lane)] = w.y;
      }
    }
    wave_lds_fence();
#pragma unroll 1
    for (int ii = 0; ii < 16; ++ii) {  // all lanes: Y[row][lane]; 2 lanes/bank = free
      const float* Wrow = lds + (ii << 6);
      float acc0 = 0.0f, acc1 = 0.0f;
#pragma unroll
      for (int t = 0; t < 32; ++t) {
        acc0 = fmaf(Wrow[lane ^ (2 * t)], v2[t].x, acc0);
        acc1 = fmaf(Wrow[lane ^ (2 * t + 1)], v2[t].y, acc1);
      }
      Og[((tt << 4) + ii) * 64 + lane] = acc0 + acc1;
    }
    wave_lds_fence();  // reads done before next tile overwrites
  }
}

extern "C" void kernel_launch(void* const* d_in, const int* in_sizes, int n_in,
                              void* d_out, int out_size, void* d_ws, size_t ws_size,
                              hipStream_t stream) {
  const float* X = (const float*)d_in[0];
  float* out = (float*)d_out;
  const int nmat = in_sizes[0] / NN;  // 8192
  logeig_jacobi_pk4<<<nmat / 4, 256, 0, stream>>>(X, out);
}

// Round 7
// 5791.677 us; speedup vs baseline: 4.9600x; 1.0122x over previous
//
#include <hip/hip_runtime.h>
#include <math.h>

#define NN 4096
#define MAX_SWEEPS 12

typedef float f2 __attribute__((ext_vector_type(2)));

// psi(k) = alpha*k in GF(2^6), primitive poly x^6 + x + 1. Orbit of 1 = all 63 masks.
constexpr int psi_step(int k) { return ((k << 1) & 63) ^ ((k & 32) ? 3 : 0); }
struct CycTab {
  int c[63];
  constexpr CycTab() : c{} {
    int x = 1;
    for (int j = 0; j < 63; ++j) { c[j] = x; x = psi_step(x); }
  }
};
static constexpr CycTab CYC{};

__device__ __forceinline__ float bperm(int addr, float x) {
  return __int_as_float(__builtin_amdgcn_ds_bpermute(addr, __float_as_int(x)));
}
// Within-wave LDS fence (per-wave private LDS; no inter-wave blocking).
__device__ __forceinline__ void wave_lds_fence() {
  asm volatile("s_waitcnt lgkmcnt(0)" ::: "memory");
}
__device__ __forceinline__ float fast_rcp(float x) {
  float r; asm("v_rcp_f32 %0, %1" : "=v"(r) : "v"(x)); return r;
}

// cs={c,s}, xy={x,y} -> {c*x - s*y, s*x + c*y}   (2 packed-f32 ops)
__device__ __forceinline__ f2 colrot(f2 cs, f2 xy) {
  f2 t, d;
  asm("v_pk_mul_f32 %0, %1, %2 op_sel:[1,1] op_sel_hi:[0,1] neg_lo:[1,0]"
      : "=v"(t) : "v"(cs), "v"(xy));
  asm("v_pk_fma_f32 %0, %1, %2, %3 op_sel:[0,0,0] op_sel_hi:[1,0,1]"
      : "=v"(d) : "v"(cs), "v"(xy), "v"(t));
  return d;
}
// Partner-replica column rotation: cs={c,st}, xy={a,b} -> {c*a + st*b, -st*a + c*b}.
// Exactly reproduces (same products, same fma order) what the partner lane
// computes with its own table entry {c, -st} -- so the row phase can consume
// locally-rotated raw partner values, bit-identical to the R6 dataflow.
__device__ __forceinline__ f2 colrotP(f2 cs, f2 xy) {
  f2 t, d;
  // t = { st*b, c*b }
  asm("v_pk_mul_f32 %0, %1, %2 op_sel:[1,1] op_sel_hi:[0,1]"
      : "=v"(t) : "v"(cs), "v"(xy));
  // d = { c*a + t.lo, -st*a + t.hi }
  asm("v_pk_fma_f32 %0, %1, %2, %3 op_sel:[0,0,0] op_sel_hi:[1,0,1] neg_hi:[1,0,0]"
      : "=v"(d) : "v"(cs), "v"(xy), "v"(t));
  return d;
}
// cs={c,st}, a, p -> {c*a.x - st*p.y, c*a.y - st*p.x}   (row mix; p = partner post slot)
__device__ __forceinline__ f2 rowrot(f2 cs, f2 a, f2 p) {
  f2 t, d;
  asm("v_pk_mul_f32 %0, %1, %2 op_sel:[1,1] op_sel_hi:[1,0] neg_lo:[1,0] neg_hi:[1,0]"
      : "=v"(t) : "v"(cs), "v"(p));
  asm("v_pk_fma_f32 %0, %1, %2, %3 op_sel:[0,0,0] op_sel_hi:[0,1,1]"
      : "=v"(d) : "v"(cs), "v"(a), "v"(t));
  return d;
}

// 4 waves / 256-thread block, ONE MATRIX PER WAVE, private LDS slices.
// R7 restructure: fused column+row update per slot (partner raw gather +
// colrotP replica), cross-round angle prefetch, rcp-shortened angle chain.
// Rotation schedule and arithmetic identical to the verified R6 kernel.
__global__ __launch_bounds__(256, 2) void logeig_jacobi_pk4(
    const float* __restrict__ X, float* __restrict__ out) {
  __shared__ float SH[4][1024];  // per-wave 4 KB staging (prologue/epilogue)
  __shared__ f2 ANG[4][64];      // per-wave per-round angle table {c, st}
  const int tid = threadIdx.x;
  const int lane = tid & 63;
  const int wid = tid >> 6;
  const size_t base = ((size_t)blockIdx.x * 4 + wid) * NN;
  float* lds = SH[wid];
  f2* ang = ANG[wid];

  f2 a2[32], v2[32];

  // ---- prologue: stage 16 rows (4 KB) at a time; lane extracts its row in XOR layout ----
  {
    const float4* Xg = (const float4*)(X + base);
    float4* L4 = (float4*)lds;
    for (int ch = 0; ch < 4; ++ch) {
#pragma unroll
      for (int i = 0; i < 4; ++i) L4[lane + 64 * i] = Xg[ch * 256 + lane + 64 * i];
      wave_lds_fence();
      if ((lane >> 4) == ch) {  // my row lives in this chunk
        const int lr = (lane & 15) << 6;
#pragma unroll
        for (int r = 0; r < 64; ++r) {  // 16 lanes -> 16 distinct banks: conflict-free
          const float val = lds[lr + (lane ^ r)];
          if (r & 1) a2[r >> 1].y = val; else a2[r >> 1].x = val;
        }
      }
      wave_lds_fence();  // reads done before next chunk overwrites
    }
  }
#pragma unroll
  for (int t = 1; t < 32; ++t) { v2[t].x = 0.0f; v2[t].y = 0.0f; }
  v2[0].x = 1.0f; v2[0].y = 0.0f;

  // phi state (wave-uniform -> SGPRs): m = phi(1); Bj = phi(2^{j+1}).
  int m = 1, B0 = 2, B1 = 4, B2 = 8, B3 = 16, B4 = 32;

  // Round-0 angle-input prefetch (mask 1).
  float otdg_pf = bperm((lane ^ 1) << 2, a2[0].x);
  float sym_pf  = bperm((lane ^ 1) << 2, a2[0].y);

#pragma unroll 1
  for (int sw = 0; sw < MAX_SWEEPS; ++sw) {
#pragma unroll 1
    for (int rr = 0; rr < 63; ++rr) {
      const int maddr = (lane ^ m) << 2;
      // ---- angles (inputs prefetched last round; apq symmetrized) ----
      const float mydg = a2[0].x;
      const float apq = 0.5f * (a2[0].y + sym_pf);
      const bool isq = (lane ^ m) < lane;
      const float app = isq ? otdg_pf : mydg;
      const float aqq = isq ? mydg : otdg_pf;
      float c = 1.0f, s = 0.0f;
      if (fabsf(apq) > 1e-37f) {
        // rcp-based: both pair lanes run identical instrs on identical inputs
        // -> bit-identical (c,s); rotation orthogonality is structural.
        const float tau = (aqq - app) * 0.5f * fast_rcp(apq);
        const float den = fabsf(tau) + sqrtf(fmaf(tau, tau, 1.0f));
        float tt = fast_rcp(den);
        tt = (tau >= 0.0f) ? tt : -tt;
        c = rsqrtf(fmaf(tt, tt, 1.0f));
        s = tt * c;
      }
      const float st = isq ? -s : s;  // sign-folded s
      const f2 cst0 = {c, st};
      ang[lane] = cst0;   // publish for column-phase gathers
      wave_lds_fence();   // only the table write outstanding here

      // ---- fused column+row update, Gray-ordered slots ----
      // praw = partner's RAW slot (pre-round values -> independent of this
      // round's math; bperms overlap the rotation VALU stream). colrotP
      // reproduces the partner's column rotation bit-exactly; rowrot then
      // mixes rows exactly as the R6 two-phase version did.
      {
        const int Bv[5] = {B0, B1, B2, B3, B4};
        int ui = lane;  // lane ^ u, Gray-walked
#pragma unroll
        for (int t = 0; t < 32; ++t) {
          const int slot = t ^ (t >> 1);
          f2 praw;
          praw.x = bperm(maddr, a2[slot].x);
          praw.y = bperm(maddr, a2[slot].y);
          const f2 csg = (t == 0) ? cst0 : ang[ui];
          const f2 tmp = colrot(csg, a2[slot]);
          const f2 prt = colrotP(csg, praw);
          a2[slot] = rowrot(cst0, tmp, prt);
          v2[slot] = colrot(csg, v2[slot]);
          if (t == 1) {
            // slots 0,1 are final: prefetch next round's angle inputs
            // (next diag = a2[0].x fixed under relabel; next a[1] = a[psi(1)]
            //  = a[2] = a2[1].x; next mask = B0).
            const int pmaddr = (lane ^ B0) << 2;
            otdg_pf = bperm(pmaddr, a2[0].x);
            sym_pf  = bperm(pmaddr, a2[1].x);
          }
          if (t < 31) ui ^= Bv[__builtin_ctz(t + 1)];
        }
      }

      // ---- relabel a[k] <- a[psi(k)] (fixed 63-cycle, component-static) ----
      {
        const int h = CYC.c[0];
        const float ta = (h & 1) ? a2[h >> 1].y : a2[h >> 1].x;
        const float tv = (h & 1) ? v2[h >> 1].y : v2[h >> 1].x;
#pragma unroll
        for (int j = 0; j < 62; ++j) {
          const int dd = CYC.c[j], ss2 = CYC.c[j + 1];
          const float sa = (ss2 & 1) ? a2[ss2 >> 1].y : a2[ss2 >> 1].x;
          const float sv = (ss2 & 1) ? v2[ss2 >> 1].y : v2[ss2 >> 1].x;
          if (dd & 1) { a2[dd >> 1].y = sa; v2[dd >> 1].y = sv; }
          else        { a2[dd >> 1].x = sa; v2[dd >> 1].x = sv; }
        }
        const int l_ = CYC.c[62];
        if (l_ & 1) { a2[l_ >> 1].y = ta; v2[l_ >> 1].y = tv; }
        else        { a2[l_ >> 1].x = ta; v2[l_ >> 1].x = tv; }
      }

      // ---- advance phi ----
      const int nB4 = m ^ B0;
      m = B0; B0 = B1; B1 = B2; B2 = B3; B3 = B4; B4 = nB4;
    }

    // ---- convergence check (phi = identity here) ----
    float offs = a2[0].y * a2[0].y, dias = a2[0].x * a2[0].x;
#pragma unroll
    for (int t = 1; t < 32; ++t) {
      offs = fmaf(a2[t].x, a2[t].x, offs);
      offs = fmaf(a2[t].y, a2[t].y, offs);
    }
#pragma unroll
    for (int o = 1; o < 64; o <<= 1) {  // butterfly: all lanes identical -> uniform branch
      offs += __shfl_xor(offs, o);
      dias += __shfl_xor(dias, o);
    }
    if (offs <= 1e-13f * dias) break;
  }

  // ---- epilogue: Y = V diag(log lam) V^T, tiled 16 rows / 4 KB, per-wave private ----
  const float ll = logf(fmaxf(a2[0].x, 1e-30f));  // clamp: never NaN/inf
  // a2 is dead: reuse as la[r] = log lam of column lane^r
#pragma unroll
  for (int r = 0; r < 64; ++r) {
    const float lr_ = __shfl_xor(ll, r);
    if (r & 1) a2[r >> 1].y = lr_; else a2[r >> 1].x = lr_;
  }
  float* Og = out + base;
  for (int tt = 0; tt < 4; ++tt) {
    if ((lane >> 4) == tt) {  // write W rows of this tile (16 lanes, distinct banks)
      const int lr = (lane & 15) << 6;
#pragma unroll
      for (int t = 0; t < 32; ++t) {
        const f2 w = v2[t] * a2[t];
        lds[lr + ((2 * t) ^ lane)] = w.x;
        lds[lr + ((2 * t + 1) ^ lane)] = w.y;
      }
    }
    wave_lds_fence();
#pragma unroll 1
    for (int ii = 0; ii < 16; ++ii) {  // all lanes: Y[row][lane]; 2 lanes/bank = free
      const float* Wrow = lds + (ii << 6);
      float acc0 = 0.0f, acc1 = 0.0f;
#pragma unroll
      for (int t = 0; t < 32; ++t) {
        acc0 = fmaf(Wrow[lane ^ (2 * t)], v2[t].x, acc0);
        acc1 = fmaf(Wrow[lane ^ (2 * t + 1)], v2[t].y, acc1);
      }
      Og[((tt << 4) + ii) * 64 + lane] = acc0 + acc1;
    }
    wave_lds_fence();  // reads done before next tile overwrites
  }
}

extern "C" void kernel_launch(void* const* d_in, const int* in_sizes, int n_in,
                              void* d_out, int out_size, void* d_ws, size_t ws_size,
                              hipStream_t stream) {
  const float* X = (const float*)d_in[0];
  float* out = (float*)d_out;
  const int nmat = in_sizes[0] / NN;  // 8192
  logeig_jacobi_pk4<<<nmat / 4, 256, 0, stream>>>(X, out);
}